// Round 14
// baseline (370.221 us; speedup 1.0000x reference)
//
#include <hip/hip_runtime.h>
#include <stdint.h>

// Problem constants (fixed by reference): B=8192 samples, D=512 dims, 100 classes.
#define BSZ   8192
#define DIM   512

typedef __attribute__((ext_vector_type(8))) short short8;      // 8 bf16 MFMA A/B frag
typedef __attribute__((ext_vector_type(4))) float f32x4;       // MFMA C/D frag
typedef __attribute__((ext_vector_type(8))) uint16_t u16x8;    // 16B of bf16 payload

__host__ __device__ inline uint16_t f2bf(float x) {
  uint32_t u = __float_as_uint(x);
  return (uint16_t)((u + 0x7FFFu + ((u >> 16) & 1u)) >> 16);
}
__host__ __device__ inline float bf2f(uint16_t h) {
  return __uint_as_float(((uint32_t)h) << 16);
}

// ---------------------------------------------------------------------------
// Threefry-2x32-20 (exact JAX semantics, partitionable mode: bits = y0 ^ y1).
// ---------------------------------------------------------------------------
__host__ __device__ inline uint32_t rotl32(uint32_t v, int s) {
#if defined(__HIP_DEVICE_COMPILE__) && __has_builtin(__builtin_amdgcn_alignbit)
  return __builtin_amdgcn_alignbit(v, v, 32 - s);
#else
  return (v << s) | (v >> (32 - s));
#endif
}

__host__ __device__ inline void threefry2x32(uint32_t k0, uint32_t k1,
                                             uint32_t x0, uint32_t x1,
                                             uint32_t& o0, uint32_t& o1) {
  uint32_t ks2 = k0 ^ k1 ^ 0x1BD11BDAu;
  x0 += k0; x1 += k1;
  x0 += x1; x1 = rotl32(x1, 13); x1 ^= x0;
  x0 += x1; x1 = rotl32(x1, 15); x1 ^= x0;
  x0 += x1; x1 = rotl32(x1, 26); x1 ^= x0;
  x0 += x1; x1 = rotl32(x1,  6); x1 ^= x0;
  x0 += k1; x1 += ks2 + 1u;
  x0 += x1; x1 = rotl32(x1, 17); x1 ^= x0;
  x0 += x1; x1 = rotl32(x1, 29); x1 ^= x0;
  x0 += x1; x1 = rotl32(x1, 16); x1 ^= x0;
  x0 += x1; x1 = rotl32(x1, 24); x1 ^= x0;
  x0 += ks2; x1 += k0 + 2u;
  x0 += x1; x1 = rotl32(x1, 13); x1 ^= x0;
  x0 += x1; x1 = rotl32(x1, 15); x1 ^= x0;
  x0 += x1; x1 = rotl32(x1, 26); x1 ^= x0;
  x0 += x1; x1 = rotl32(x1,  6); x1 ^= x0;
  x0 += k0; x1 += k1 + 3u;
  x0 += x1; x1 = rotl32(x1, 17); x1 ^= x0;
  x0 += x1; x1 = rotl32(x1, 29); x1 ^= x0;
  x0 += x1; x1 = rotl32(x1, 16); x1 ^= x0;
  x0 += x1; x1 = rotl32(x1, 24); x1 ^= x0;
  x0 += k1; x1 += ks2 + 4u;
  x0 += x1; x1 = rotl32(x1, 13); x1 ^= x0;
  x0 += x1; x1 = rotl32(x1, 15); x1 ^= x0;
  x0 += x1; x1 = rotl32(x1, 26); x1 ^= x0;
  x0 += x1; x1 = rotl32(x1,  6); x1 ^= x0;
  x0 += ks2; x1 += k0 + 5u;
  o0 = x0; o1 = x1;
}

// ---------------------------------------------------------------------------
// Workspace layout (bytes), r13-proven. Mpart (4 x 1 MB f32 split-K) ALIASES
// Hb: consumed by buildG before the overlap kernel writes Hb.
// ---------------------------------------------------------------------------
constexpr size_t OFF_CTR    = 0;         // 1 int (negmax work-steal counter), zeroed
constexpr size_t OFF_DONE   = 4;         // 1 int (loss last-block counter), zeroed
constexpr size_t OFF_S      = 1024;      // 512 f32, zeroed
constexpr size_t OFF_BSTART = 3072;      // 101 ints
constexpr size_t OFF_BIDX   = 4096;      // 8192 ints
constexpr size_t OFF_PIDX   = 36864;     // 8192 ints
constexpr size_t OFF_NIDX   = 69632;     // 8192 ints (ends 102400)
constexpr size_t OFF_LPART  = 102400;    // 2048 float2 (ends 118784)
constexpr size_t OFF_GB     = 131072;    // 512x512 bf16 metric
constexpr size_t OFF_FB     = 2097152;   // 8192x512 bf16 F (8 MB)
constexpr size_t OFF_HB     = 10485760;  // 8192x512 bf16 H (8 MB) / Mpart alias
constexpr size_t ZERO_BYTES = 3072;      // ctr + done + S

// ---------------------------------------------------------------------------
// Kernel 1: prep — convert F->Fb (all 2048 blocks) + colsum (blocks 0..255).
// (r13 proven, verbatim)
// ---------------------------------------------------------------------------
__global__ __launch_bounds__(256) void prep_kernel(const float* __restrict__ F,
                                                   uint16_t* __restrict__ Fb,
                                                   float* __restrict__ S) {
  int i = (blockIdx.x * 256 + threadIdx.x) * 8;
  float4 a = *(const float4*)&F[i];
  float4 b = *(const float4*)&F[i + 4];
  u16x8 o;
  o[0] = f2bf(a.x); o[1] = f2bf(a.y); o[2] = f2bf(a.z); o[3] = f2bf(a.w);
  o[4] = f2bf(b.x); o[5] = f2bf(b.y); o[6] = f2bf(b.z); o[7] = f2bf(b.w);
  *(u16x8*)&Fb[i] = o;
  if (blockIdx.x < 256) {
    int b0 = blockIdx.x * 32;
    int t = threadIdx.x;
    float s0 = 0.f, s1 = 0.f;
    for (int r = 0; r < 32; ++r) {
      const float* row = F + (size_t)(b0 + r) * DIM;
      s0 += row[t];
      s1 += row[t + 256];
    }
    atomicAdd(&S[t], s0);
    atomicAdd(&S[t + 256], s1);
  }
}

// ---------------------------------------------------------------------------
// Kernel 2: covmat (SYMMETRIC: 36 upper-triangle tiles only — M = F^T F is
// symmetric, buildG mirrors) + bucket fused as block 144. Grid 145 x 256.
// covmat body = r11/r13 proven MFMA body; bucket body = r7 proven.
// ---------------------------------------------------------------------------
union CovShared {
  struct { uint16_t sA[64][40]; uint16_t sB[64][40]; } mm;   // 10,240 B
  struct { int cnt[128]; int base[128]; } bk;                 // 1,024 B
};

__global__ __launch_bounds__(256) void covmat_bucket_kernel(
    const uint16_t* __restrict__ Fb, float* __restrict__ Mpart,
    const int* __restrict__ labels, int* __restrict__ bucketStart,
    int* __restrict__ bucketIdx) {
  __shared__ CovShared sh;
  int bid = blockIdx.x, tid = threadIdx.x;
  if (bid < 144) {
    int chunk = bid & 3;
    int t = bid >> 2;                 // 0..35 upper-triangle tile
    int rem = t, ti = 0;
    while (rem >= 8 - ti) { rem -= 8 - ti; ++ti; }
    int tj = ti + rem;                // tj >= ti
    int i0 = ti * 64, j0 = tj * 64;
    int kc0 = chunk * 2048;
    int lane = tid & 63, wid = tid >> 6, quad = lane >> 4, l16 = lane & 15;
    int wm = (wid >> 1) * 32, wn = (wid & 1) * 32;
    int sk = tid & 31, sm = (tid >> 5) * 8;
    f32x4 acc[2][2] = {};
    for (int kk = 0; kk < 2048; kk += 32) {
      int krow = kc0 + kk + sk;
      u16x8 va = *(const u16x8*)&Fb[(size_t)krow * DIM + i0 + sm];
      u16x8 vb = *(const u16x8*)&Fb[(size_t)krow * DIM + j0 + sm];
      __syncthreads();
#pragma unroll
      for (int jj = 0; jj < 8; ++jj) { sh.mm.sA[sm + jj][sk] = va[jj]; sh.mm.sB[sm + jj][sk] = vb[jj]; }
      __syncthreads();
#pragma unroll
      for (int r = 0; r < 2; ++r) {
        short8 af = *(short8*)&sh.mm.sA[wm + r * 16 + l16][quad * 8];
#pragma unroll
        for (int c = 0; c < 2; ++c) {
          short8 bf = *(short8*)&sh.mm.sB[wn + c * 16 + l16][quad * 8];
          acc[r][c] = __builtin_amdgcn_mfma_f32_16x16x32_bf16(af, bf, acc[r][c], 0, 0, 0);
        }
      }
    }
    float* outp = Mpart + (size_t)chunk * DIM * DIM;
#pragma unroll
    for (int r = 0; r < 2; ++r)
#pragma unroll
      for (int c = 0; c < 2; ++c)
#pragma unroll
        for (int g = 0; g < 4; ++g)
          outp[(size_t)(i0 + wm + r * 16 + quad * 4 + g) * DIM + j0 + wn + c * 16 + l16] = acc[r][c][g];
  } else {
    // bucket (r7 proven body)
    if (tid < 128) sh.bk.cnt[tid] = 0;
    __syncthreads();
    for (int b = tid; b < BSZ; b += 256) atomicAdd(&sh.bk.cnt[labels[b]], 1);
    __syncthreads();
    if (tid == 0) {
      int run = 0;
      for (int c = 0; c < 100; ++c) { sh.bk.base[c] = run; bucketStart[c] = run; run += sh.bk.cnt[c]; }
      bucketStart[100] = run;
    }
    __syncthreads();
    for (int b = tid; b < BSZ; b += 256) {
      int p = atomicAdd(&sh.bk.base[labels[b]], 1);
      bucketIdx[p] = b;
    }
  }
}

// ---------------------------------------------------------------------------
// Kernel 3: buildG — reads the symmetric element (min,max); M[a][b]=M[b][a].
// ---------------------------------------------------------------------------
__global__ __launch_bounds__(256) void buildG_kernel(const float* __restrict__ Mpart,
                                                     const float* __restrict__ S,
                                                     uint16_t* __restrict__ Gb) {
  int idx = blockIdx.x * 256 + threadIdx.x;
  int i = idx >> 9, j = idx & 511;
  int a = i < j ? i : j;
  int b = i < j ? j : i;
  size_t sidx = (size_t)a * DIM + b;
  float m = Mpart[sidx] + Mpart[(size_t)DIM * DIM + sidx] +
            Mpart[2 * (size_t)DIM * DIM + sidx] + Mpart[3 * (size_t)DIM * DIM + sidx];
  const float invB = 1.0f / (float)BSZ;
  float mi = S[i] * invB, mj = S[j] * invB;
  Gb[idx] = f2bf(m * invB - mi * mj + (i == j ? 1.0f : 0.0f));
}

// ---------------------------------------------------------------------------
// Kernel 4: OVERLAP (r13 proven, verbatim): matmulH [0,224) / posmax [224,256)
// / negmax work-steal (all 1024 blocks).
// ---------------------------------------------------------------------------
struct SharedMM  { uint16_t sA[128][72]; uint16_t sB[64][72]; };
struct SharedNeg { uint8_t slab[BSZ]; unsigned long long wmax[4]; int curRow; };
union __align__(16) SharedU { SharedMM mm; SharedNeg neg; };

__global__ __launch_bounds__(256) void overlap_kernel(
    const uint16_t* __restrict__ Fb, const uint16_t* __restrict__ Gb,
    uint16_t* __restrict__ Hb, const int* __restrict__ labels,
    const int* __restrict__ bStart, const int* __restrict__ bIdx,
    int* __restrict__ posIdx, int* __restrict__ negIdx,
    int* __restrict__ rowCtr,
    uint32_t kp0, uint32_t kp1, uint32_t kn0, uint32_t kn1) {
  __shared__ SharedU sh;
  int bid = blockIdx.x, tid = threadIdx.x;
  int lane = tid & 63, wid = tid >> 6, quad = lane >> 4, l16 = lane & 15;

  if (bid < 224) {
    int am = tid & 127, ah = (tid >> 7) * 32;
    int bk = tid >> 2, bn = (tid & 3) * 16;
    int tm = wid * 32;
    for (int t = bid; t < 512; t += 224) {
      int n0 = (t & 7) * 64;
      int m0 = (t >> 3) * 128;
      f32x4 acc[2][4] = {};
      for (int k0 = 0; k0 < DIM; k0 += 64) {
        {
          const uint16_t* src = &Fb[(size_t)(m0 + am) * DIM + k0 + ah];
#pragma unroll
          for (int v = 0; v < 4; ++v)
            *(u16x8*)&sh.mm.sA[am][ah + v * 8] = *(const u16x8*)&src[v * 8];
        }
        {
          u16x8 g0 = *(const u16x8*)&Gb[(size_t)(k0 + bk) * DIM + n0 + bn];
          u16x8 g1 = *(const u16x8*)&Gb[(size_t)(k0 + bk) * DIM + n0 + bn + 8];
#pragma unroll
          for (int jj = 0; jj < 8; ++jj) { sh.mm.sB[bn + jj][bk] = g0[jj]; sh.mm.sB[bn + 8 + jj][bk] = g1[jj]; }
        }
        __syncthreads();
#pragma unroll
        for (int k32 = 0; k32 < 64; k32 += 32) {
          short8 af[2];
#pragma unroll
          for (int r = 0; r < 2; ++r)
            af[r] = *(short8*)&sh.mm.sA[tm + r * 16 + l16][k32 + quad * 8];
#pragma unroll
          for (int c = 0; c < 4; ++c) {
            short8 bf = *(short8*)&sh.mm.sB[c * 16 + l16][k32 + quad * 8];
#pragma unroll
            for (int r = 0; r < 2; ++r)
              acc[r][c] = __builtin_amdgcn_mfma_f32_16x16x32_bf16(af[r], bf, acc[r][c], 0, 0, 0);
          }
        }
        __syncthreads();
      }
#pragma unroll
      for (int r = 0; r < 2; ++r)
#pragma unroll
        for (int c = 0; c < 4; ++c)
#pragma unroll
          for (int g = 0; g < 4; ++g)
            Hb[(size_t)(m0 + tm + r * 16 + quad * 4 + g) * DIM + n0 + c * 16 + l16] = f2bf(acc[r][c][g]);
    }
    __syncthreads();
  } else if (bid < 256) {
    for (int row = (bid - 224) * 4 + wid; row < BSZ; row += 128) {
      int cls = labels[row];
      int s = bStart[cls], e = bStart[cls + 1];
      uint32_t base = (uint32_t)(row << 13);
      unsigned long long best = 0;
      for (int t2 = s + lane; t2 < e; t2 += 64) {
        int cc = bIdx[t2];
        uint32_t a0, a1;
        threefry2x32(kp0, kp1, 0u, base + (uint32_t)cc, a0, a1);
        unsigned long long comp = ((unsigned long long)((a0 ^ a1) >> 9) << 32) | (uint32_t)(~cc);
        if (cc == row) comp = 0;
        if (comp > best) best = comp;
      }
#pragma unroll
      for (int off = 32; off; off >>= 1) {
        unsigned long long o = __shfl_down(best, off);
        if (o > best) best = o;
      }
      if (lane == 0) posIdx[row] = best ? (int)(~(uint32_t)best) : -1;
    }
    __syncthreads();
  }

  {
    uint32_t* s32 = (uint32_t*)sh.neg.slab;
#pragma unroll
    for (int pass = 0; pass < 8; ++pass) {
      int idx = pass * 1024 + tid * 4;
      int4 l4 = *(const int4*)&labels[idx];
      uint32_t packed = (uint32_t)(l4.x & 0xFF) | ((uint32_t)(l4.y & 0xFF) << 8) |
                        ((uint32_t)(l4.z & 0xFF) << 16) | ((uint32_t)(l4.w & 0xFF) << 24);
      s32[pass * 256 + tid] = packed;
    }
  }
  __syncthreads();
  while (true) {
    if (tid == 0) sh.neg.curRow = atomicAdd(rowCtr, 1);
    __syncthreads();
    int row = sh.neg.curRow;
    if (row >= BSZ) break;
    uint32_t li = sh.neg.slab[row];
    uint32_t base = (uint32_t)(row << 13);
    unsigned long long bA = 0, bB = 0, bC = 0, bD = 0;
#pragma unroll 2
    for (int it = 0; it < 8; ++it) {
      int c0 = tid + (it << 10);
      int c1 = c0 + 256, c2 = c0 + 512, c3 = c0 + 768;
      uint32_t l0 = sh.neg.slab[c0], l1 = sh.neg.slab[c1], l2 = sh.neg.slab[c2], l3 = sh.neg.slab[c3];
      uint32_t a0, a1, e0, e1, f0, f1, g0, g1;
      threefry2x32(kn0, kn1, 0u, base + (uint32_t)c0, a0, a1);
      threefry2x32(kn0, kn1, 0u, base + (uint32_t)c1, e0, e1);
      threefry2x32(kn0, kn1, 0u, base + (uint32_t)c2, f0, f1);
      threefry2x32(kn0, kn1, 0u, base + (uint32_t)c3, g0, g1);
      unsigned long long compA = ((unsigned long long)((a0 ^ a1) >> 9) << 32) | (uint32_t)(~c0);
      unsigned long long compB = ((unsigned long long)((e0 ^ e1) >> 9) << 32) | (uint32_t)(~c1);
      unsigned long long compC = ((unsigned long long)((f0 ^ f1) >> 9) << 32) | (uint32_t)(~c2);
      unsigned long long compD = ((unsigned long long)((g0 ^ g1) >> 9) << 32) | (uint32_t)(~c3);
      if (l0 == li) compA = 0;
      if (l1 == li) compB = 0;
      if (l2 == li) compC = 0;
      if (l3 == li) compD = 0;
      if (compA > bA) bA = compA;
      if (compB > bB) bB = compB;
      if (compC > bC) bC = compC;
      if (compD > bD) bD = compD;
    }
    if (bB > bA) bA = bB;
    if (bC > bA) bA = bC;
    if (bD > bA) bA = bD;
    unsigned long long best = bA;
#pragma unroll
    for (int off = 32; off; off >>= 1) {
      unsigned long long o = __shfl_down(best, off);
      if (o > best) best = o;
    }
    if (lane == 0) sh.neg.wmax[wid] = best;
    __syncthreads();
    if (tid == 0) {
      best = sh.neg.wmax[0];
      for (int w = 1; w < 4; ++w) if (sh.neg.wmax[w] > best) best = sh.neg.wmax[w];
      negIdx[row] = best ? (int)(~(uint32_t)best) : -1;
    }
    __syncthreads();
  }
}

// ---------------------------------------------------------------------------
// Kernel 5: loss (reads Fb bf16 — half the gather bytes) + fused finalize via
// last-block counter. grid 2048.
// ---------------------------------------------------------------------------
__global__ __launch_bounds__(256) void loss_final_kernel(
    const uint16_t* __restrict__ Fb, const uint16_t* __restrict__ Hb,
    const int* __restrict__ posIdx, const int* __restrict__ negIdx,
    float2* __restrict__ lossPart, int* __restrict__ doneCtr,
    float* __restrict__ out) {
  __shared__ float2 part[4];
  __shared__ bool isLast;
  int row = blockIdx.x * 4 + (threadIdx.x >> 6);
  int lane = threadIdx.x & 63;
  int p = posIdx[row], n = negIdx[row];
  bool valid = (p >= 0) && (n >= 0);
  int ps = valid ? p : row;
  int ns = valid ? n : row;
  int k = lane * 8;
  u16x8 f_i = *(const u16x8*)(Fb + (size_t)row * DIM + k);
  u16x8 f_p = *(const u16x8*)(Fb + (size_t)ps * DIM + k);
  u16x8 f_n = *(const u16x8*)(Fb + (size_t)ns * DIM + k);
  u16x8 h_i = *(const u16x8*)(Hb + (size_t)row * DIM + k);
  u16x8 h_p = *(const u16x8*)(Hb + (size_t)ps * DIM + k);
  u16x8 h_n = *(const u16x8*)(Hb + (size_t)ns * DIM + k);
  float qii = 0.f, qpp = 0.f, qip = 0.f, qnn = 0.f, qin = 0.f;
#pragma unroll
  for (int jj = 0; jj < 8; ++jj) {
    float fi = bf2f(f_i[jj]), fp = bf2f(f_p[jj]), fn = bf2f(f_n[jj]);
    float hi = bf2f(h_i[jj]), hp = bf2f(h_p[jj]), hn = bf2f(h_n[jj]);
    qii += fi * hi;
    qpp += fp * hp;
    qip += fi * hp;
    qnn += fn * hn;
    qin += fi * hn;
  }
#pragma unroll
  for (int off = 32; off > 0; off >>= 1) {
    qii += __shfl_down(qii, off);
    qpp += __shfl_down(qpp, off);
    qip += __shfl_down(qip, off);
    qnn += __shfl_down(qnn, off);
    qin += __shfl_down(qin, off);
  }
  if (lane == 0) {
    float d2p = fmaxf(qii + qpp - 2.f * qip, 0.f);
    float d2n = fmaxf(qii + qnn - 2.f * qin, 0.f);
    float v = fmaxf(sqrtf(d2p + 1e-8f) - sqrtf(d2n + 1e-8f) + 1.0f, 0.0f);
    if (!valid) v = 0.f;
    part[threadIdx.x >> 6] = make_float2(v, valid ? 1.f : 0.f);
  }
  __syncthreads();
  if (threadIdx.x == 0) {
    float s = 0.f, c = 0.f;
#pragma unroll
    for (int w = 0; w < 4; ++w) { s += part[w].x; c += part[w].y; }
    lossPart[blockIdx.x] = make_float2(s, c);
    __threadfence();
    isLast = (atomicAdd(doneCtr, 1) == 2047);
  }
  __syncthreads();
  if (isLast) {
    __threadfence();
    int tid = threadIdx.x;
    float s = 0.f, c = 0.f;
    for (int z = tid; z < 2048; z += 256) {
      float2 v = lossPart[z];
      s += v.x; c += v.y;
    }
#pragma unroll
    for (int off = 32; off > 0; off >>= 1) {
      s += __shfl_down(s, off);
      c += __shfl_down(c, off);
    }
    if (lane == 0) part[tid >> 6] = make_float2(s, c);
    __syncthreads();
    if (tid == 0) {
      s = 0.f; c = 0.f;
#pragma unroll
      for (int w = 0; w < 4; ++w) { s += part[w].x; c += part[w].y; }
      out[0] = s / fmaxf(c, 1.0f);
    }
  }
}

// ---------------------------------------------------------------------------
extern "C" void kernel_launch(void* const* d_in, const int* in_sizes, int n_in,
                              void* d_out, int out_size, void* d_ws, size_t ws_size,
                              hipStream_t stream) {
  const float* F = (const float*)d_in[0];
  const int* labels = (const int*)d_in[1];
  float* out = (float*)d_out;
  char* ws = (char*)d_ws;

  int* rowCtr    = (int*)(ws + OFF_CTR);
  int* doneCtr   = (int*)(ws + OFF_DONE);
  float* S       = (float*)(ws + OFF_S);
  int* bStart    = (int*)(ws + OFF_BSTART);
  int* bIdx      = (int*)(ws + OFF_BIDX);
  int* posIdx    = (int*)(ws + OFF_PIDX);
  int* negIdx    = (int*)(ws + OFF_NIDX);
  float2* lPart  = (float2*)(ws + OFF_LPART);
  uint16_t* Gb   = (uint16_t*)(ws + OFF_GB);
  uint16_t* Fb   = (uint16_t*)(ws + OFF_FB);
  uint16_t* Hb   = (uint16_t*)(ws + OFF_HB);
  float* Mpart   = (float*)(ws + OFF_HB);   // consumed before Hb is written

  // Partitionable (foldlike) split of jax.random.key(42):
  uint32_t kp0, kp1, kn0, kn1;
  threefry2x32(0u, 42u, 0u, 0u, kp0, kp1);
  threefry2x32(0u, 42u, 0u, 1u, kn0, kn1);

  hipMemsetAsync(ws, 0, ZERO_BYTES, stream);

  prep_kernel<<<2048, 256, 0, stream>>>(F, Fb, S);

  covmat_bucket_kernel<<<145, 256, 0, stream>>>(Fb, Mpart, labels, bStart, bIdx);

  buildG_kernel<<<(DIM * DIM) / 256, 256, 0, stream>>>(Mpart, S, Gb);

  overlap_kernel<<<1024, 256, 0, stream>>>(Fb, Gb, Hb, labels, bStart, bIdx,
                                           posIdx, negIdx, rowCtr,
                                           kp0, kp1, kn0, kn1);

  loss_final_kernel<<<BSZ / 4, 256, 0, stream>>>(Fb, Hb, posIdx, negIdx,
                                                 lPart, doneCtr, out);
}

// Round 15
// 366.398 us; speedup vs baseline: 1.0104x; 1.0104x over previous
//
#include <hip/hip_runtime.h>
#include <stdint.h>

// Problem constants (fixed by reference): B=8192 samples, D=512 dims, 100 classes.
#define BSZ   8192
#define DIM   512

typedef __attribute__((ext_vector_type(8))) short short8;      // 8 bf16 MFMA A/B frag
typedef __attribute__((ext_vector_type(4))) float f32x4;       // MFMA C/D frag
typedef __attribute__((ext_vector_type(8))) uint16_t u16x8;    // 16B of bf16 payload

__host__ __device__ inline uint16_t f2bf(float x) {
  uint32_t u = __float_as_uint(x);
  return (uint16_t)((u + 0x7FFFu + ((u >> 16) & 1u)) >> 16);
}
__host__ __device__ inline float bf2f(uint16_t h) {
  return __uint_as_float(((uint32_t)h) << 16);
}

// ---------------------------------------------------------------------------
// Threefry-2x32-20 (exact JAX semantics, partitionable mode: bits = y0 ^ y1).
// ---------------------------------------------------------------------------
__host__ __device__ inline uint32_t rotl32(uint32_t v, int s) {
#if defined(__HIP_DEVICE_COMPILE__) && __has_builtin(__builtin_amdgcn_alignbit)
  return __builtin_amdgcn_alignbit(v, v, 32 - s);
#else
  return (v << s) | (v >> (32 - s));
#endif
}

__host__ __device__ inline void threefry2x32(uint32_t k0, uint32_t k1,
                                             uint32_t x0, uint32_t x1,
                                             uint32_t& o0, uint32_t& o1) {
  uint32_t ks2 = k0 ^ k1 ^ 0x1BD11BDAu;
  x0 += k0; x1 += k1;
  x0 += x1; x1 = rotl32(x1, 13); x1 ^= x0;
  x0 += x1; x1 = rotl32(x1, 15); x1 ^= x0;
  x0 += x1; x1 = rotl32(x1, 26); x1 ^= x0;
  x0 += x1; x1 = rotl32(x1,  6); x1 ^= x0;
  x0 += k1; x1 += ks2 + 1u;
  x0 += x1; x1 = rotl32(x1, 17); x1 ^= x0;
  x0 += x1; x1 = rotl32(x1, 29); x1 ^= x0;
  x0 += x1; x1 = rotl32(x1, 16); x1 ^= x0;
  x0 += x1; x1 = rotl32(x1, 24); x1 ^= x0;
  x0 += ks2; x1 += k0 + 2u;
  x0 += x1; x1 = rotl32(x1, 13); x1 ^= x0;
  x0 += x1; x1 = rotl32(x1, 15); x1 ^= x0;
  x0 += x1; x1 = rotl32(x1, 26); x1 ^= x0;
  x0 += x1; x1 = rotl32(x1,  6); x1 ^= x0;
  x0 += k0; x1 += k1 + 3u;
  x0 += x1; x1 = rotl32(x1, 17); x1 ^= x0;
  x0 += x1; x1 = rotl32(x1, 29); x1 ^= x0;
  x0 += x1; x1 = rotl32(x1, 16); x1 ^= x0;
  x0 += x1; x1 = rotl32(x1, 24); x1 ^= x0;
  x0 += k1; x1 += ks2 + 4u;
  x0 += x1; x1 = rotl32(x1, 13); x1 ^= x0;
  x0 += x1; x1 = rotl32(x1, 15); x1 ^= x0;
  x0 += x1; x1 = rotl32(x1, 26); x1 ^= x0;
  x0 += x1; x1 = rotl32(x1,  6); x1 ^= x0;
  x0 += ks2; x1 += k0 + 5u;
  o0 = x0; o1 = x1;
}

// ---------------------------------------------------------------------------
// Workspace layout (bytes), r13-proven (+ DONE counter). Mpart (4 x 1 MB f32
// split-K) ALIASES Hb: consumed by buildG before overlap writes Hb.
// ---------------------------------------------------------------------------
constexpr size_t OFF_CTR    = 0;         // 1 int (negmax work-steal counter), zeroed
constexpr size_t OFF_DONE   = 4;         // 1 int (loss last-block counter), zeroed
constexpr size_t OFF_S      = 1024;      // 512 f32, zeroed
constexpr size_t OFF_BSTART = 3072;      // 101 ints
constexpr size_t OFF_BIDX   = 4096;      // 8192 ints
constexpr size_t OFF_PIDX   = 36864;     // 8192 ints
constexpr size_t OFF_NIDX   = 69632;     // 8192 ints (ends 102400)
constexpr size_t OFF_LPART  = 102400;    // 2048 float2 (ends 118784)
constexpr size_t OFF_GB     = 131072;    // 512x512 bf16 metric
constexpr size_t OFF_FB     = 2097152;   // 8192x512 bf16 F (8 MB)
constexpr size_t OFF_HB     = 10485760;  // 8192x512 bf16 H (8 MB) / Mpart alias
constexpr size_t ZERO_BYTES = 3072;      // ctr + done + S

// ---------------------------------------------------------------------------
// Kernel 1: prep — convert F->Fb (all 2048 blocks) + colsum (blocks 0..255).
// (r13 proven, verbatim)
// ---------------------------------------------------------------------------
__global__ __launch_bounds__(256) void prep_kernel(const float* __restrict__ F,
                                                   uint16_t* __restrict__ Fb,
                                                   float* __restrict__ S) {
  int i = (blockIdx.x * 256 + threadIdx.x) * 8;
  float4 a = *(const float4*)&F[i];
  float4 b = *(const float4*)&F[i + 4];
  u16x8 o;
  o[0] = f2bf(a.x); o[1] = f2bf(a.y); o[2] = f2bf(a.z); o[3] = f2bf(a.w);
  o[4] = f2bf(b.x); o[5] = f2bf(b.y); o[6] = f2bf(b.z); o[7] = f2bf(b.w);
  *(u16x8*)&Fb[i] = o;
  if (blockIdx.x < 256) {
    int b0 = blockIdx.x * 32;
    int t = threadIdx.x;
    float s0 = 0.f, s1 = 0.f;
    for (int r = 0; r < 32; ++r) {
      const float* row = F + (size_t)(b0 + r) * DIM;
      s0 += row[t];
      s1 += row[t + 256];
    }
    atomicAdd(&S[t], s0);
    atomicAdd(&S[t + 256], s1);
  }
}

// ---------------------------------------------------------------------------
// Kernel 2: covmat — FULL 256-tile grid (r13-proven MFMA body; flattened 1D
// grid) + bucket fused as block 256 (r7-proven body). Grid 257 x 256.
// REVERTED from r14: no symmetric-tile reduction (its coalescing-hostile
// buildG mirror was the prime regression suspect, −38 us).
// ---------------------------------------------------------------------------
union CovShared {
  struct { uint16_t sA[64][40]; uint16_t sB[64][40]; } mm;   // 10,240 B
  struct { int cnt[128]; int base[128]; } bk;                 // 1,024 B
};

__global__ __launch_bounds__(256) void covmat_bucket_kernel(
    const uint16_t* __restrict__ Fb, float* __restrict__ Mpart,
    const int* __restrict__ labels, int* __restrict__ bucketStart,
    int* __restrict__ bucketIdx) {
  __shared__ CovShared sh;
  int bid = blockIdx.x, tid = threadIdx.x;
  if (bid < 256) {
    int chunk = bid & 3;
    int tile = bid >> 2;              // 0..63 full tile grid
    int i0 = (tile >> 3) * 64, j0 = (tile & 7) * 64;
    int kc0 = chunk * 2048;
    int lane = tid & 63, wid = tid >> 6, quad = lane >> 4, l16 = lane & 15;
    int wm = (wid >> 1) * 32, wn = (wid & 1) * 32;
    int sk = tid & 31, sm = (tid >> 5) * 8;
    f32x4 acc[2][2] = {};
    for (int kk = 0; kk < 2048; kk += 32) {
      int krow = kc0 + kk + sk;
      u16x8 va = *(const u16x8*)&Fb[(size_t)krow * DIM + i0 + sm];
      u16x8 vb = *(const u16x8*)&Fb[(size_t)krow * DIM + j0 + sm];
      __syncthreads();
#pragma unroll
      for (int jj = 0; jj < 8; ++jj) { sh.mm.sA[sm + jj][sk] = va[jj]; sh.mm.sB[sm + jj][sk] = vb[jj]; }
      __syncthreads();
#pragma unroll
      for (int r = 0; r < 2; ++r) {
        short8 af = *(short8*)&sh.mm.sA[wm + r * 16 + l16][quad * 8];
#pragma unroll
        for (int c = 0; c < 2; ++c) {
          short8 bf = *(short8*)&sh.mm.sB[wn + c * 16 + l16][quad * 8];
          acc[r][c] = __builtin_amdgcn_mfma_f32_16x16x32_bf16(af, bf, acc[r][c], 0, 0, 0);
        }
      }
    }
    float* outp = Mpart + (size_t)chunk * DIM * DIM;
#pragma unroll
    for (int r = 0; r < 2; ++r)
#pragma unroll
      for (int c = 0; c < 2; ++c)
#pragma unroll
        for (int g = 0; g < 4; ++g)
          outp[(size_t)(i0 + wm + r * 16 + quad * 4 + g) * DIM + j0 + wn + c * 16 + l16] = acc[r][c][g];
  } else {
    // bucket (r7 proven body)
    if (tid < 128) sh.bk.cnt[tid] = 0;
    __syncthreads();
    for (int b = tid; b < BSZ; b += 256) atomicAdd(&sh.bk.cnt[labels[b]], 1);
    __syncthreads();
    if (tid == 0) {
      int run = 0;
      for (int c = 0; c < 100; ++c) { sh.bk.base[c] = run; bucketStart[c] = run; run += sh.bk.cnt[c]; }
      bucketStart[100] = run;
    }
    __syncthreads();
    for (int b = tid; b < BSZ; b += 256) {
      int p = atomicAdd(&sh.bk.base[labels[b]], 1);
      bucketIdx[p] = b;
    }
  }
}

// ---------------------------------------------------------------------------
// Kernel 3: buildG (r13 proven, verbatim — direct coalesced reads).
// ---------------------------------------------------------------------------
__global__ __launch_bounds__(256) void buildG_kernel(const float* __restrict__ Mpart,
                                                     const float* __restrict__ S,
                                                     uint16_t* __restrict__ Gb) {
  int idx = blockIdx.x * 256 + threadIdx.x;
  int i = idx >> 9, j = idx & 511;
  float m = Mpart[idx] + Mpart[(size_t)DIM * DIM + idx] +
            Mpart[2 * (size_t)DIM * DIM + idx] + Mpart[3 * (size_t)DIM * DIM + idx];
  const float invB = 1.0f / (float)BSZ;
  float mi = S[i] * invB, mj = S[j] * invB;
  Gb[idx] = f2bf(m * invB - mi * mj + (i == j ? 1.0f : 0.0f));
}

// ---------------------------------------------------------------------------
// Kernel 4: OVERLAP (r13 proven, verbatim): matmulH [0,224) / posmax [224,256)
// / negmax work-steal (all 1024 blocks).
// ---------------------------------------------------------------------------
struct SharedMM  { uint16_t sA[128][72]; uint16_t sB[64][72]; };
struct SharedNeg { uint8_t slab[BSZ]; unsigned long long wmax[4]; int curRow; };
union __align__(16) SharedU { SharedMM mm; SharedNeg neg; };

__global__ __launch_bounds__(256) void overlap_kernel(
    const uint16_t* __restrict__ Fb, const uint16_t* __restrict__ Gb,
    uint16_t* __restrict__ Hb, const int* __restrict__ labels,
    const int* __restrict__ bStart, const int* __restrict__ bIdx,
    int* __restrict__ posIdx, int* __restrict__ negIdx,
    int* __restrict__ rowCtr,
    uint32_t kp0, uint32_t kp1, uint32_t kn0, uint32_t kn1) {
  __shared__ SharedU sh;
  int bid = blockIdx.x, tid = threadIdx.x;
  int lane = tid & 63, wid = tid >> 6, quad = lane >> 4, l16 = lane & 15;

  if (bid < 224) {
    int am = tid & 127, ah = (tid >> 7) * 32;
    int bk = tid >> 2, bn = (tid & 3) * 16;
    int tm = wid * 32;
    for (int t = bid; t < 512; t += 224) {
      int n0 = (t & 7) * 64;
      int m0 = (t >> 3) * 128;
      f32x4 acc[2][4] = {};
      for (int k0 = 0; k0 < DIM; k0 += 64) {
        {
          const uint16_t* src = &Fb[(size_t)(m0 + am) * DIM + k0 + ah];
#pragma unroll
          for (int v = 0; v < 4; ++v)
            *(u16x8*)&sh.mm.sA[am][ah + v * 8] = *(const u16x8*)&src[v * 8];
        }
        {
          u16x8 g0 = *(const u16x8*)&Gb[(size_t)(k0 + bk) * DIM + n0 + bn];
          u16x8 g1 = *(const u16x8*)&Gb[(size_t)(k0 + bk) * DIM + n0 + bn + 8];
#pragma unroll
          for (int jj = 0; jj < 8; ++jj) { sh.mm.sB[bn + jj][bk] = g0[jj]; sh.mm.sB[bn + 8 + jj][bk] = g1[jj]; }
        }
        __syncthreads();
#pragma unroll
        for (int k32 = 0; k32 < 64; k32 += 32) {
          short8 af[2];
#pragma unroll
          for (int r = 0; r < 2; ++r)
            af[r] = *(short8*)&sh.mm.sA[tm + r * 16 + l16][k32 + quad * 8];
#pragma unroll
          for (int c = 0; c < 4; ++c) {
            short8 bf = *(short8*)&sh.mm.sB[c * 16 + l16][k32 + quad * 8];
#pragma unroll
            for (int r = 0; r < 2; ++r)
              acc[r][c] = __builtin_amdgcn_mfma_f32_16x16x32_bf16(af[r], bf, acc[r][c], 0, 0, 0);
          }
        }
        __syncthreads();
      }
#pragma unroll
      for (int r = 0; r < 2; ++r)
#pragma unroll
        for (int c = 0; c < 4; ++c)
#pragma unroll
          for (int g = 0; g < 4; ++g)
            Hb[(size_t)(m0 + tm + r * 16 + quad * 4 + g) * DIM + n0 + c * 16 + l16] = f2bf(acc[r][c][g]);
    }
    __syncthreads();
  } else if (bid < 256) {
    for (int row = (bid - 224) * 4 + wid; row < BSZ; row += 128) {
      int cls = labels[row];
      int s = bStart[cls], e = bStart[cls + 1];
      uint32_t base = (uint32_t)(row << 13);
      unsigned long long best = 0;
      for (int t2 = s + lane; t2 < e; t2 += 64) {
        int cc = bIdx[t2];
        uint32_t a0, a1;
        threefry2x32(kp0, kp1, 0u, base + (uint32_t)cc, a0, a1);
        unsigned long long comp = ((unsigned long long)((a0 ^ a1) >> 9) << 32) | (uint32_t)(~cc);
        if (cc == row) comp = 0;
        if (comp > best) best = comp;
      }
#pragma unroll
      for (int off = 32; off; off >>= 1) {
        unsigned long long o = __shfl_down(best, off);
        if (o > best) best = o;
      }
      if (lane == 0) posIdx[row] = best ? (int)(~(uint32_t)best) : -1;
    }
    __syncthreads();
  }

  {
    uint32_t* s32 = (uint32_t*)sh.neg.slab;
#pragma unroll
    for (int pass = 0; pass < 8; ++pass) {
      int idx = pass * 1024 + tid * 4;
      int4 l4 = *(const int4*)&labels[idx];
      uint32_t packed = (uint32_t)(l4.x & 0xFF) | ((uint32_t)(l4.y & 0xFF) << 8) |
                        ((uint32_t)(l4.z & 0xFF) << 16) | ((uint32_t)(l4.w & 0xFF) << 24);
      s32[pass * 256 + tid] = packed;
    }
  }
  __syncthreads();
  while (true) {
    if (tid == 0) sh.neg.curRow = atomicAdd(rowCtr, 1);
    __syncthreads();
    int row = sh.neg.curRow;
    if (row >= BSZ) break;
    uint32_t li = sh.neg.slab[row];
    uint32_t base = (uint32_t)(row << 13);
    unsigned long long bA = 0, bB = 0, bC = 0, bD = 0;
#pragma unroll 2
    for (int it = 0; it < 8; ++it) {
      int c0 = tid + (it << 10);
      int c1 = c0 + 256, c2 = c0 + 512, c3 = c0 + 768;
      uint32_t l0 = sh.neg.slab[c0], l1 = sh.neg.slab[c1], l2 = sh.neg.slab[c2], l3 = sh.neg.slab[c3];
      uint32_t a0, a1, e0, e1, f0, f1, g0, g1;
      threefry2x32(kn0, kn1, 0u, base + (uint32_t)c0, a0, a1);
      threefry2x32(kn0, kn1, 0u, base + (uint32_t)c1, e0, e1);
      threefry2x32(kn0, kn1, 0u, base + (uint32_t)c2, f0, f1);
      threefry2x32(kn0, kn1, 0u, base + (uint32_t)c3, g0, g1);
      unsigned long long compA = ((unsigned long long)((a0 ^ a1) >> 9) << 32) | (uint32_t)(~c0);
      unsigned long long compB = ((unsigned long long)((e0 ^ e1) >> 9) << 32) | (uint32_t)(~c1);
      unsigned long long compC = ((unsigned long long)((f0 ^ f1) >> 9) << 32) | (uint32_t)(~c2);
      unsigned long long compD = ((unsigned long long)((g0 ^ g1) >> 9) << 32) | (uint32_t)(~c3);
      if (l0 == li) compA = 0;
      if (l1 == li) compB = 0;
      if (l2 == li) compC = 0;
      if (l3 == li) compD = 0;
      if (compA > bA) bA = compA;
      if (compB > bB) bB = compB;
      if (compC > bC) bC = compC;
      if (compD > bD) bD = compD;
    }
    if (bB > bA) bA = bB;
    if (bC > bA) bA = bC;
    if (bD > bA) bA = bD;
    unsigned long long best = bA;
#pragma unroll
    for (int off = 32; off; off >>= 1) {
      unsigned long long o = __shfl_down(best, off);
      if (o > best) best = o;
    }
    if (lane == 0) sh.neg.wmax[wid] = best;
    __syncthreads();
    if (tid == 0) {
      best = sh.neg.wmax[0];
      for (int w = 1; w < 4; ++w) if (sh.neg.wmax[w] > best) best = sh.neg.wmax[w];
      negIdx[row] = best ? (int)(~(uint32_t)best) : -1;
    }
    __syncthreads();
  }
}

// ---------------------------------------------------------------------------
// Kernel 5: loss (reads Fb bf16 — half the gather bytes) + fused finalize via
// last-block counter. grid 2048. (r14 body — outputs were bit-correct there.)
// ---------------------------------------------------------------------------
__global__ __launch_bounds__(256) void loss_final_kernel(
    const uint16_t* __restrict__ Fb, const uint16_t* __restrict__ Hb,
    const int* __restrict__ posIdx, const int* __restrict__ negIdx,
    float2* __restrict__ lossPart, int* __restrict__ doneCtr,
    float* __restrict__ out) {
  __shared__ float2 part[4];
  __shared__ bool isLast;
  int row = blockIdx.x * 4 + (threadIdx.x >> 6);
  int lane = threadIdx.x & 63;
  int p = posIdx[row], n = negIdx[row];
  bool valid = (p >= 0) && (n >= 0);
  int ps = valid ? p : row;
  int ns = valid ? n : row;
  int k = lane * 8;
  u16x8 f_i = *(const u16x8*)(Fb + (size_t)row * DIM + k);
  u16x8 f_p = *(const u16x8*)(Fb + (size_t)ps * DIM + k);
  u16x8 f_n = *(const u16x8*)(Fb + (size_t)ns * DIM + k);
  u16x8 h_i = *(const u16x8*)(Hb + (size_t)row * DIM + k);
  u16x8 h_p = *(const u16x8*)(Hb + (size_t)ps * DIM + k);
  u16x8 h_n = *(const u16x8*)(Hb + (size_t)ns * DIM + k);
  float qii = 0.f, qpp = 0.f, qip = 0.f, qnn = 0.f, qin = 0.f;
#pragma unroll
  for (int jj = 0; jj < 8; ++jj) {
    float fi = bf2f(f_i[jj]), fp = bf2f(f_p[jj]), fn = bf2f(f_n[jj]);
    float hi = bf2f(h_i[jj]), hp = bf2f(h_p[jj]), hn = bf2f(h_n[jj]);
    qii += fi * hi;
    qpp += fp * hp;
    qip += fi * hp;
    qnn += fn * hn;
    qin += fi * hn;
  }
#pragma unroll
  for (int off = 32; off > 0; off >>= 1) {
    qii += __shfl_down(qii, off);
    qpp += __shfl_down(qpp, off);
    qip += __shfl_down(qip, off);
    qnn += __shfl_down(qnn, off);
    qin += __shfl_down(qin, off);
  }
  if (lane == 0) {
    float d2p = fmaxf(qii + qpp - 2.f * qip, 0.f);
    float d2n = fmaxf(qii + qnn - 2.f * qin, 0.f);
    float v = fmaxf(sqrtf(d2p + 1e-8f) - sqrtf(d2n + 1e-8f) + 1.0f, 0.0f);
    if (!valid) v = 0.f;
    part[threadIdx.x >> 6] = make_float2(v, valid ? 1.f : 0.f);
  }
  __syncthreads();
  if (threadIdx.x == 0) {
    float s = 0.f, c = 0.f;
#pragma unroll
    for (int w = 0; w < 4; ++w) { s += part[w].x; c += part[w].y; }
    lossPart[blockIdx.x] = make_float2(s, c);
    __threadfence();
    isLast = (atomicAdd(doneCtr, 1) == 2047);
  }
  __syncthreads();
  if (isLast) {
    __threadfence();
    int tid = threadIdx.x;
    float s = 0.f, c = 0.f;
    for (int z = tid; z < 2048; z += 256) {
      float2 v = lossPart[z];
      s += v.x; c += v.y;
    }
#pragma unroll
    for (int off = 32; off > 0; off >>= 1) {
      s += __shfl_down(s, off);
      c += __shfl_down(c, off);
    }
    if (lane == 0) part[tid >> 6] = make_float2(s, c);
    __syncthreads();
    if (tid == 0) {
      s = 0.f; c = 0.f;
#pragma unroll
      for (int w = 0; w < 4; ++w) { s += part[w].x; c += part[w].y; }
      out[0] = s / fmaxf(c, 1.0f);
    }
  }
}

// ---------------------------------------------------------------------------
extern "C" void kernel_launch(void* const* d_in, const int* in_sizes, int n_in,
                              void* d_out, int out_size, void* d_ws, size_t ws_size,
                              hipStream_t stream) {
  const float* F = (const float*)d_in[0];
  const int* labels = (const int*)d_in[1];
  float* out = (float*)d_out;
  char* ws = (char*)d_ws;

  int* rowCtr    = (int*)(ws + OFF_CTR);
  int* doneCtr   = (int*)(ws + OFF_DONE);
  float* S       = (float*)(ws + OFF_S);
  int* bStart    = (int*)(ws + OFF_BSTART);
  int* bIdx      = (int*)(ws + OFF_BIDX);
  int* posIdx    = (int*)(ws + OFF_PIDX);
  int* negIdx    = (int*)(ws + OFF_NIDX);
  float2* lPart  = (float2*)(ws + OFF_LPART);
  uint16_t* Gb   = (uint16_t*)(ws + OFF_GB);
  uint16_t* Fb   = (uint16_t*)(ws + OFF_FB);
  uint16_t* Hb   = (uint16_t*)(ws + OFF_HB);
  float* Mpart   = (float*)(ws + OFF_HB);   // consumed before Hb is written

  // Partitionable (foldlike) split of jax.random.key(42):
  uint32_t kp0, kp1, kn0, kn1;
  threefry2x32(0u, 42u, 0u, 0u, kp0, kp1);
  threefry2x32(0u, 42u, 0u, 1u, kn0, kn1);

  hipMemsetAsync(ws, 0, ZERO_BYTES, stream);

  prep_kernel<<<2048, 256, 0, stream>>>(F, Fb, S);

  covmat_bucket_kernel<<<257, 256, 0, stream>>>(Fb, Mpart, labels, bStart, bIdx);

  buildG_kernel<<<(DIM * DIM) / 256, 256, 0, stream>>>(Mpart, S, Gb);

  overlap_kernel<<<1024, 256, 0, stream>>>(Fb, Gb, Hb, labels, bStart, bIdx,
                                           posIdx, negIdx, rowCtr,
                                           kp0, kp1, kn0, kn1);

  loss_final_kernel<<<BSZ / 4, 256, 0, stream>>>(Fb, Hb, posIdx, negIdx,
                                                 lPart, doneCtr, out);
}

// Round 16
// 312.812 us; speedup vs baseline: 1.1835x; 1.1713x over previous
//
#include <hip/hip_runtime.h>
#include <stdint.h>

// Problem constants (fixed by reference): B=8192 samples, D=512 dims, 100 classes.
#define BSZ   8192
#define DIM   512

typedef __attribute__((ext_vector_type(8))) short short8;      // 8 bf16 MFMA A/B frag
typedef __attribute__((ext_vector_type(4))) float f32x4;       // MFMA C/D frag
typedef __attribute__((ext_vector_type(8))) uint16_t u16x8;    // 16B of bf16 payload

__host__ __device__ inline uint16_t f2bf(float x) {
  uint32_t u = __float_as_uint(x);
  return (uint16_t)((u + 0x7FFFu + ((u >> 16) & 1u)) >> 16);
}
__host__ __device__ inline float bf2f(uint16_t h) {
  return __uint_as_float(((uint32_t)h) << 16);
}

// ---------------------------------------------------------------------------
// Threefry-2x32-20 (exact JAX semantics, partitionable mode: bits = y0 ^ y1).
// ---------------------------------------------------------------------------
__host__ __device__ inline uint32_t rotl32(uint32_t v, int s) {
#if defined(__HIP_DEVICE_COMPILE__) && __has_builtin(__builtin_amdgcn_alignbit)
  return __builtin_amdgcn_alignbit(v, v, 32 - s);
#else
  return (v << s) | (v >> (32 - s));
#endif
}

__host__ __device__ inline void threefry2x32(uint32_t k0, uint32_t k1,
                                             uint32_t x0, uint32_t x1,
                                             uint32_t& o0, uint32_t& o1) {
  uint32_t ks2 = k0 ^ k1 ^ 0x1BD11BDAu;
  x0 += k0; x1 += k1;
  x0 += x1; x1 = rotl32(x1, 13); x1 ^= x0;
  x0 += x1; x1 = rotl32(x1, 15); x1 ^= x0;
  x0 += x1; x1 = rotl32(x1, 26); x1 ^= x0;
  x0 += x1; x1 = rotl32(x1,  6); x1 ^= x0;
  x0 += k1; x1 += ks2 + 1u;
  x0 += x1; x1 = rotl32(x1, 17); x1 ^= x0;
  x0 += x1; x1 = rotl32(x1, 29); x1 ^= x0;
  x0 += x1; x1 = rotl32(x1, 16); x1 ^= x0;
  x0 += x1; x1 = rotl32(x1, 24); x1 ^= x0;
  x0 += ks2; x1 += k0 + 2u;
  x0 += x1; x1 = rotl32(x1, 13); x1 ^= x0;
  x0 += x1; x1 = rotl32(x1, 15); x1 ^= x0;
  x0 += x1; x1 = rotl32(x1, 26); x1 ^= x0;
  x0 += x1; x1 = rotl32(x1,  6); x1 ^= x0;
  x0 += k0; x1 += k1 + 3u;
  x0 += x1; x1 = rotl32(x1, 17); x1 ^= x0;
  x0 += x1; x1 = rotl32(x1, 29); x1 ^= x0;
  x0 += x1; x1 = rotl32(x1, 16); x1 ^= x0;
  x0 += x1; x1 = rotl32(x1, 24); x1 ^= x0;
  x0 += k1; x1 += ks2 + 4u;
  x0 += x1; x1 = rotl32(x1, 13); x1 ^= x0;
  x0 += x1; x1 = rotl32(x1, 15); x1 ^= x0;
  x0 += x1; x1 = rotl32(x1, 26); x1 ^= x0;
  x0 += x1; x1 = rotl32(x1,  6); x1 ^= x0;
  x0 += ks2; x1 += k0 + 5u;
  o0 = x0; o1 = x1;
}

// ---------------------------------------------------------------------------
// Workspace layout (bytes), r13-proven. Mpart (4 x 1 MB f32 split-K) ALIASES
// Hb: consumed by buildG before overlap writes Hb.
// ---------------------------------------------------------------------------
constexpr size_t OFF_CTR    = 0;         // 1 int (negmax work-steal counter), zeroed
constexpr size_t OFF_S      = 1024;      // 512 f32, zeroed
constexpr size_t OFF_BSTART = 3072;      // 101 ints
constexpr size_t OFF_BIDX   = 4096;      // 8192 ints
constexpr size_t OFF_PIDX   = 36864;     // 8192 ints
constexpr size_t OFF_NIDX   = 69632;     // 8192 ints (ends 102400)
constexpr size_t OFF_LPART  = 102400;    // 2048 float2 (ends 118784)
constexpr size_t OFF_GB     = 131072;    // 512x512 bf16 metric
constexpr size_t OFF_FB     = 2097152;   // 8192x512 bf16 F (8 MB)
constexpr size_t OFF_HB     = 10485760;  // 8192x512 bf16 H (8 MB) / Mpart alias
constexpr size_t ZERO_BYTES = 3072;      // ctr + S

// ---------------------------------------------------------------------------
// Kernel 1: prep — convert F->Fb (all 2048 blocks) + colsum (blocks 0..255).
// (r13 proven, verbatim)
// ---------------------------------------------------------------------------
__global__ __launch_bounds__(256) void prep_kernel(const float* __restrict__ F,
                                                   uint16_t* __restrict__ Fb,
                                                   float* __restrict__ S) {
  int i = (blockIdx.x * 256 + threadIdx.x) * 8;
  float4 a = *(const float4*)&F[i];
  float4 b = *(const float4*)&F[i + 4];
  u16x8 o;
  o[0] = f2bf(a.x); o[1] = f2bf(a.y); o[2] = f2bf(a.z); o[3] = f2bf(a.w);
  o[4] = f2bf(b.x); o[5] = f2bf(b.y); o[6] = f2bf(b.z); o[7] = f2bf(b.w);
  *(u16x8*)&Fb[i] = o;
  if (blockIdx.x < 256) {
    int b0 = blockIdx.x * 32;
    int t = threadIdx.x;
    float s0 = 0.f, s1 = 0.f;
    for (int r = 0; r < 32; ++r) {
      const float* row = F + (size_t)(b0 + r) * DIM;
      s0 += row[t];
      s1 += row[t + 256];
    }
    atomicAdd(&S[t], s0);
    atomicAdd(&S[t + 256], s1);
  }
}

// ---------------------------------------------------------------------------
// Kernel 2: covmat (full 256-tile grid, r13-proven MFMA body) + bucket fused
// as block 256 (r7-proven body; correct in r14/r15, absmax 0). Grid 257.
// ---------------------------------------------------------------------------
union CovShared {
  struct { uint16_t sA[64][40]; uint16_t sB[64][40]; } mm;   // 10,240 B
  struct { int cnt[128]; int base[128]; } bk;                 // 1,024 B
};

__global__ __launch_bounds__(256) void covmat_bucket_kernel(
    const uint16_t* __restrict__ Fb, float* __restrict__ Mpart,
    const int* __restrict__ labels, int* __restrict__ bucketStart,
    int* __restrict__ bucketIdx) {
  __shared__ CovShared sh;
  int bid = blockIdx.x, tid = threadIdx.x;
  if (bid < 256) {
    int chunk = bid & 3;
    int tile = bid >> 2;
    int i0 = (tile >> 3) * 64, j0 = (tile & 7) * 64;
    int kc0 = chunk * 2048;
    int lane = tid & 63, wid = tid >> 6, quad = lane >> 4, l16 = lane & 15;
    int wm = (wid >> 1) * 32, wn = (wid & 1) * 32;
    int sk = tid & 31, sm = (tid >> 5) * 8;
    f32x4 acc[2][2] = {};
    for (int kk = 0; kk < 2048; kk += 32) {
      int krow = kc0 + kk + sk;
      u16x8 va = *(const u16x8*)&Fb[(size_t)krow * DIM + i0 + sm];
      u16x8 vb = *(const u16x8*)&Fb[(size_t)krow * DIM + j0 + sm];
      __syncthreads();
#pragma unroll
      for (int jj = 0; jj < 8; ++jj) { sh.mm.sA[sm + jj][sk] = va[jj]; sh.mm.sB[sm + jj][sk] = vb[jj]; }
      __syncthreads();
#pragma unroll
      for (int r = 0; r < 2; ++r) {
        short8 af = *(short8*)&sh.mm.sA[wm + r * 16 + l16][quad * 8];
#pragma unroll
        for (int c = 0; c < 2; ++c) {
          short8 bf = *(short8*)&sh.mm.sB[wn + c * 16 + l16][quad * 8];
          acc[r][c] = __builtin_amdgcn_mfma_f32_16x16x32_bf16(af, bf, acc[r][c], 0, 0, 0);
        }
      }
    }
    float* outp = Mpart + (size_t)chunk * DIM * DIM;
#pragma unroll
    for (int r = 0; r < 2; ++r)
#pragma unroll
      for (int c = 0; c < 2; ++c)
#pragma unroll
        for (int g = 0; g < 4; ++g)
          outp[(size_t)(i0 + wm + r * 16 + quad * 4 + g) * DIM + j0 + wn + c * 16 + l16] = acc[r][c][g];
  } else {
    if (tid < 128) sh.bk.cnt[tid] = 0;
    __syncthreads();
    for (int b = tid; b < BSZ; b += 256) atomicAdd(&sh.bk.cnt[labels[b]], 1);
    __syncthreads();
    if (tid == 0) {
      int run = 0;
      for (int c = 0; c < 100; ++c) { sh.bk.base[c] = run; bucketStart[c] = run; run += sh.bk.cnt[c]; }
      bucketStart[100] = run;
    }
    __syncthreads();
    for (int b = tid; b < BSZ; b += 256) {
      int p = atomicAdd(&sh.bk.base[labels[b]], 1);
      bucketIdx[p] = b;
    }
  }
}

// ---------------------------------------------------------------------------
// Kernel 3: buildG (r13 proven, verbatim — direct coalesced reads).
// ---------------------------------------------------------------------------
__global__ __launch_bounds__(256) void buildG_kernel(const float* __restrict__ Mpart,
                                                     const float* __restrict__ S,
                                                     uint16_t* __restrict__ Gb) {
  int idx = blockIdx.x * 256 + threadIdx.x;
  int i = idx >> 9, j = idx & 511;
  float m = Mpart[idx] + Mpart[(size_t)DIM * DIM + idx] +
            Mpart[2 * (size_t)DIM * DIM + idx] + Mpart[3 * (size_t)DIM * DIM + idx];
  const float invB = 1.0f / (float)BSZ;
  float mi = S[i] * invB, mj = S[j] * invB;
  Gb[idx] = f2bf(m * invB - mi * mj + (i == j ? 1.0f : 0.0f));
}

// ---------------------------------------------------------------------------
// Kernel 4: OVERLAP (r13 proven, verbatim): matmulH [0,224) / posmax [224,256)
// / negmax work-steal (all 1024 blocks).
// ---------------------------------------------------------------------------
struct SharedMM  { uint16_t sA[128][72]; uint16_t sB[64][72]; };
struct SharedNeg { uint8_t slab[BSZ]; unsigned long long wmax[4]; int curRow; };
union __align__(16) SharedU { SharedMM mm; SharedNeg neg; };

__global__ __launch_bounds__(256) void overlap_kernel(
    const uint16_t* __restrict__ Fb, const uint16_t* __restrict__ Gb,
    uint16_t* __restrict__ Hb, const int* __restrict__ labels,
    const int* __restrict__ bStart, const int* __restrict__ bIdx,
    int* __restrict__ posIdx, int* __restrict__ negIdx,
    int* __restrict__ rowCtr,
    uint32_t kp0, uint32_t kp1, uint32_t kn0, uint32_t kn1) {
  __shared__ SharedU sh;
  int bid = blockIdx.x, tid = threadIdx.x;
  int lane = tid & 63, wid = tid >> 6, quad = lane >> 4, l16 = lane & 15;

  if (bid < 224) {
    int am = tid & 127, ah = (tid >> 7) * 32;
    int bk = tid >> 2, bn = (tid & 3) * 16;
    int tm = wid * 32;
    for (int t = bid; t < 512; t += 224) {
      int n0 = (t & 7) * 64;
      int m0 = (t >> 3) * 128;
      f32x4 acc[2][4] = {};
      for (int k0 = 0; k0 < DIM; k0 += 64) {
        {
          const uint16_t* src = &Fb[(size_t)(m0 + am) * DIM + k0 + ah];
#pragma unroll
          for (int v = 0; v < 4; ++v)
            *(u16x8*)&sh.mm.sA[am][ah + v * 8] = *(const u16x8*)&src[v * 8];
        }
        {
          u16x8 g0 = *(const u16x8*)&Gb[(size_t)(k0 + bk) * DIM + n0 + bn];
          u16x8 g1 = *(const u16x8*)&Gb[(size_t)(k0 + bk) * DIM + n0 + bn + 8];
#pragma unroll
          for (int jj = 0; jj < 8; ++jj) { sh.mm.sB[bn + jj][bk] = g0[jj]; sh.mm.sB[bn + 8 + jj][bk] = g1[jj]; }
        }
        __syncthreads();
#pragma unroll
        for (int k32 = 0; k32 < 64; k32 += 32) {
          short8 af[2];
#pragma unroll
          for (int r = 0; r < 2; ++r)
            af[r] = *(short8*)&sh.mm.sA[tm + r * 16 + l16][k32 + quad * 8];
#pragma unroll
          for (int c = 0; c < 4; ++c) {
            short8 bf = *(short8*)&sh.mm.sB[c * 16 + l16][k32 + quad * 8];
#pragma unroll
            for (int r = 0; r < 2; ++r)
              acc[r][c] = __builtin_amdgcn_mfma_f32_16x16x32_bf16(af[r], bf, acc[r][c], 0, 0, 0);
          }
        }
        __syncthreads();
      }
#pragma unroll
      for (int r = 0; r < 2; ++r)
#pragma unroll
        for (int c = 0; c < 4; ++c)
#pragma unroll
          for (int g = 0; g < 4; ++g)
            Hb[(size_t)(m0 + tm + r * 16 + quad * 4 + g) * DIM + n0 + c * 16 + l16] = f2bf(acc[r][c][g]);
    }
    __syncthreads();
  } else if (bid < 256) {
    for (int row = (bid - 224) * 4 + wid; row < BSZ; row += 128) {
      int cls = labels[row];
      int s = bStart[cls], e = bStart[cls + 1];
      uint32_t base = (uint32_t)(row << 13);
      unsigned long long best = 0;
      for (int t2 = s + lane; t2 < e; t2 += 64) {
        int cc = bIdx[t2];
        uint32_t a0, a1;
        threefry2x32(kp0, kp1, 0u, base + (uint32_t)cc, a0, a1);
        unsigned long long comp = ((unsigned long long)((a0 ^ a1) >> 9) << 32) | (uint32_t)(~cc);
        if (cc == row) comp = 0;
        if (comp > best) best = comp;
      }
#pragma unroll
      for (int off = 32; off; off >>= 1) {
        unsigned long long o = __shfl_down(best, off);
        if (o > best) best = o;
      }
      if (lane == 0) posIdx[row] = best ? (int)(~(uint32_t)best) : -1;
    }
    __syncthreads();
  }

  {
    uint32_t* s32 = (uint32_t*)sh.neg.slab;
#pragma unroll
    for (int pass = 0; pass < 8; ++pass) {
      int idx = pass * 1024 + tid * 4;
      int4 l4 = *(const int4*)&labels[idx];
      uint32_t packed = (uint32_t)(l4.x & 0xFF) | ((uint32_t)(l4.y & 0xFF) << 8) |
                        ((uint32_t)(l4.z & 0xFF) << 16) | ((uint32_t)(l4.w & 0xFF) << 24);
      s32[pass * 256 + tid] = packed;
    }
  }
  __syncthreads();
  while (true) {
    if (tid == 0) sh.neg.curRow = atomicAdd(rowCtr, 1);
    __syncthreads();
    int row = sh.neg.curRow;
    if (row >= BSZ) break;
    uint32_t li = sh.neg.slab[row];
    uint32_t base = (uint32_t)(row << 13);
    unsigned long long bA = 0, bB = 0, bC = 0, bD = 0;
#pragma unroll 2
    for (int it = 0; it < 8; ++it) {
      int c0 = tid + (it << 10);
      int c1 = c0 + 256, c2 = c0 + 512, c3 = c0 + 768;
      uint32_t l0 = sh.neg.slab[c0], l1 = sh.neg.slab[c1], l2 = sh.neg.slab[c2], l3 = sh.neg.slab[c3];
      uint32_t a0, a1, e0, e1, f0, f1, g0, g1;
      threefry2x32(kn0, kn1, 0u, base + (uint32_t)c0, a0, a1);
      threefry2x32(kn0, kn1, 0u, base + (uint32_t)c1, e0, e1);
      threefry2x32(kn0, kn1, 0u, base + (uint32_t)c2, f0, f1);
      threefry2x32(kn0, kn1, 0u, base + (uint32_t)c3, g0, g1);
      unsigned long long compA = ((unsigned long long)((a0 ^ a1) >> 9) << 32) | (uint32_t)(~c0);
      unsigned long long compB = ((unsigned long long)((e0 ^ e1) >> 9) << 32) | (uint32_t)(~c1);
      unsigned long long compC = ((unsigned long long)((f0 ^ f1) >> 9) << 32) | (uint32_t)(~c2);
      unsigned long long compD = ((unsigned long long)((g0 ^ g1) >> 9) << 32) | (uint32_t)(~c3);
      if (l0 == li) compA = 0;
      if (l1 == li) compB = 0;
      if (l2 == li) compC = 0;
      if (l3 == li) compD = 0;
      if (compA > bA) bA = compA;
      if (compB > bB) bB = compB;
      if (compC > bC) bC = compC;
      if (compD > bD) bD = compD;
    }
    if (bB > bA) bA = bB;
    if (bC > bA) bA = bC;
    if (bD > bA) bA = bD;
    unsigned long long best = bA;
#pragma unroll
    for (int off = 32; off; off >>= 1) {
      unsigned long long o = __shfl_down(best, off);
      if (o > best) best = o;
    }
    if (lane == 0) sh.neg.wmax[wid] = best;
    __syncthreads();
    if (tid == 0) {
      best = sh.neg.wmax[0];
      for (int w = 1; w < 4; ++w) if (sh.neg.wmax[w] > best) best = sh.neg.wmax[w];
      negIdx[row] = best ? (int)(~(uint32_t)best) : -1;
    }
    __syncthreads();
  }
}

// ---------------------------------------------------------------------------
// Kernel 5: loss — per-block float2 partial to DISTINCT addresses (r13
// structure; no global atomics, no threadfence — r15's 2048 same-address
// doneCtr atomics cost ~27 us, the r3 lesson repeated). Reads Fb (bf16,
// half the gather bytes of F). grid 2048.
// ---------------------------------------------------------------------------
__global__ __launch_bounds__(256) void loss_kernel(
    const uint16_t* __restrict__ Fb, const uint16_t* __restrict__ Hb,
    const int* __restrict__ posIdx, const int* __restrict__ negIdx,
    float2* __restrict__ lossPart) {
  __shared__ float2 part[4];
  int row = blockIdx.x * 4 + (threadIdx.x >> 6);
  int lane = threadIdx.x & 63;
  int p = posIdx[row], n = negIdx[row];
  bool valid = (p >= 0) && (n >= 0);
  int ps = valid ? p : row;
  int ns = valid ? n : row;
  int k = lane * 8;
  u16x8 f_i = *(const u16x8*)(Fb + (size_t)row * DIM + k);
  u16x8 f_p = *(const u16x8*)(Fb + (size_t)ps * DIM + k);
  u16x8 f_n = *(const u16x8*)(Fb + (size_t)ns * DIM + k);
  u16x8 h_i = *(const u16x8*)(Hb + (size_t)row * DIM + k);
  u16x8 h_p = *(const u16x8*)(Hb + (size_t)ps * DIM + k);
  u16x8 h_n = *(const u16x8*)(Hb + (size_t)ns * DIM + k);
  float qii = 0.f, qpp = 0.f, qip = 0.f, qnn = 0.f, qin = 0.f;
#pragma unroll
  for (int jj = 0; jj < 8; ++jj) {
    float fi = bf2f(f_i[jj]), fp = bf2f(f_p[jj]), fn = bf2f(f_n[jj]);
    float hi = bf2f(h_i[jj]), hp = bf2f(h_p[jj]), hn = bf2f(h_n[jj]);
    qii += fi * hi;
    qpp += fp * hp;
    qip += fi * hp;
    qnn += fn * hn;
    qin += fi * hn;
  }
#pragma unroll
  for (int off = 32; off > 0; off >>= 1) {
    qii += __shfl_down(qii, off);
    qpp += __shfl_down(qpp, off);
    qip += __shfl_down(qip, off);
    qnn += __shfl_down(qnn, off);
    qin += __shfl_down(qin, off);
  }
  if (lane == 0) {
    float d2p = fmaxf(qii + qpp - 2.f * qip, 0.f);
    float d2n = fmaxf(qii + qnn - 2.f * qin, 0.f);
    float v = fmaxf(sqrtf(d2p + 1e-8f) - sqrtf(d2n + 1e-8f) + 1.0f, 0.0f);
    if (!valid) v = 0.f;
    part[threadIdx.x >> 6] = make_float2(v, valid ? 1.f : 0.f);
  }
  __syncthreads();
  if (threadIdx.x == 0) {
    float s = 0.f, c = 0.f;
#pragma unroll
    for (int w = 0; w < 4; ++w) { s += part[w].x; c += part[w].y; }
    lossPart[blockIdx.x] = make_float2(s, c);
  }
}

// ---------------------------------------------------------------------------
// Kernel 6: finalize (r13 proven, verbatim) — 1 block reduces 2048 partials.
// ---------------------------------------------------------------------------
__global__ __launch_bounds__(256) void finalize_kernel(const float2* __restrict__ lossPart,
                                                       float* __restrict__ out) {
  __shared__ float2 wsum[4];
  int tid = threadIdx.x;
  float s = 0.f, c = 0.f;
  for (int z = tid; z < 2048; z += 256) {
    float2 v = lossPart[z];
    s += v.x; c += v.y;
  }
#pragma unroll
  for (int off = 32; off > 0; off >>= 1) {
    s += __shfl_down(s, off);
    c += __shfl_down(c, off);
  }
  if ((tid & 63) == 0) wsum[tid >> 6] = make_float2(s, c);
  __syncthreads();
  if (tid == 0) {
    s = 0.f; c = 0.f;
#pragma unroll
    for (int w = 0; w < 4; ++w) { s += wsum[w].x; c += wsum[w].y; }
    out[0] = s / fmaxf(c, 1.0f);
  }
}

// ---------------------------------------------------------------------------
extern "C" void kernel_launch(void* const* d_in, const int* in_sizes, int n_in,
                              void* d_out, int out_size, void* d_ws, size_t ws_size,
                              hipStream_t stream) {
  const float* F = (const float*)d_in[0];
  const int* labels = (const int*)d_in[1];
  float* out = (float*)d_out;
  char* ws = (char*)d_ws;

  int* rowCtr    = (int*)(ws + OFF_CTR);
  float* S       = (float*)(ws + OFF_S);
  int* bStart    = (int*)(ws + OFF_BSTART);
  int* bIdx      = (int*)(ws + OFF_BIDX);
  int* posIdx    = (int*)(ws + OFF_PIDX);
  int* negIdx    = (int*)(ws + OFF_NIDX);
  float2* lPart  = (float2*)(ws + OFF_LPART);
  uint16_t* Gb   = (uint16_t*)(ws + OFF_GB);
  uint16_t* Fb   = (uint16_t*)(ws + OFF_FB);
  uint16_t* Hb   = (uint16_t*)(ws + OFF_HB);
  float* Mpart   = (float*)(ws + OFF_HB);   // consumed before Hb is written

  // Partitionable (foldlike) split of jax.random.key(42):
  uint32_t kp0, kp1, kn0, kn1;
  threefry2x32(0u, 42u, 0u, 0u, kp0, kp1);
  threefry2x32(0u, 42u, 0u, 1u, kn0, kn1);

  hipMemsetAsync(ws, 0, ZERO_BYTES, stream);

  prep_kernel<<<2048, 256, 0, stream>>>(F, Fb, S);

  covmat_bucket_kernel<<<257, 256, 0, stream>>>(Fb, Mpart, labels, bStart, bIdx);

  buildG_kernel<<<(DIM * DIM) / 256, 256, 0, stream>>>(Mpart, S, Gb);

  overlap_kernel<<<1024, 256, 0, stream>>>(Fb, Gb, Hb, labels, bStart, bIdx,
                                           posIdx, negIdx, rowCtr,
                                           kp0, kp1, kn0, kn1);

  loss_kernel<<<BSZ / 4, 256, 0, stream>>>(Fb, Hb, posIdx, negIdx, lPart);

  finalize_kernel<<<1, 256, 0, stream>>>(lPart, out);
}